// Round 1
// baseline (243.975 us; speedup 1.0000x reference)
//
#include <hip/hip_runtime.h>
#include <math.h>

#define N_NODES 50000
#define N_EDGES 800000
#define HIDDEN  64

// ---------------- kernels ----------------

__global__ void k_zero(float* p, int n) {
    int i = blockIdx.x * blockDim.x + threadIdx.x;
    if (i < n) p[i] = 0.0f;
}

__global__ void k_deg(const int* __restrict__ col, int* __restrict__ cnt) {
    int e = blockIdx.x * blockDim.x + threadIdx.x;
    if (e < N_EDGES) atomicAdd(&cnt[col[e]], 1);
}

__global__ void k_dinv(const int* __restrict__ cnt, float* __restrict__ dinv) {
    int i = blockIdx.x * blockDim.x + threadIdx.x;
    if (i < N_NODES) dinv[i] = rsqrtf((float)(cnt[i] + 1));  // +1 self-loop
}

// layer-1 scalar scatter: t[c] += dinv[r]*x[r]
__global__ void k_scatter1(const int* __restrict__ row, const int* __restrict__ col,
                           const float* __restrict__ x, const float* __restrict__ dinv,
                           float* __restrict__ t) {
    int e = blockIdx.x * blockDim.x + threadIdx.x;
    if (e < N_EDGES) {
        int r = row[e], c = col[e];
        atomicAdd(&t[c], dinv[r] * x[r]);
    }
}

// per node: s = dinv*(t + dinv*x); h_j = relu(s*W1[j]+b1[j]); y_k = sum h_j W2[j,k];
// z_k = dinv*y_k
__global__ void k_y(const float* __restrict__ x, const float* __restrict__ dinv,
                    const float* __restrict__ t,
                    const float* __restrict__ W1, const float* __restrict__ b1,
                    const float* __restrict__ W2,
                    float* __restrict__ z0, float* __restrict__ z1) {
    int n = blockIdx.x * blockDim.x + threadIdx.x;
    if (n >= N_NODES) return;
    float di = dinv[n];
    float s  = di * (t[n] + di * x[n]);
    float y0 = 0.0f, y1 = 0.0f;
#pragma unroll
    for (int j = 0; j < HIDDEN; ++j) {
        float h = fmaxf(s * W1[j] + b1[j], 0.0f);
        y0 += h * W2[2 * j];
        y1 += h * W2[2 * j + 1];
    }
    z0[n] = di * y0;
    z1[n] = di * y1;
}

// layer-2 scatter: T_k[c] += z_k[r]
__global__ void k_scatter2(const int* __restrict__ row, const int* __restrict__ col,
                           const float* __restrict__ z0, const float* __restrict__ z1,
                           float* __restrict__ T0, float* __restrict__ T1) {
    int e = blockIdx.x * blockDim.x + threadIdx.x;
    if (e < N_EDGES) {
        int r = row[e], c = col[e];
        atomicAdd(&T0[c], z0[r]);
        atomicAdd(&T1[c], z1[r]);
    }
}

// out[c,k] = dinv[c]*(T_k[c] + z_k[c]) + b2[k]
__global__ void k_final(const float* __restrict__ dinv,
                        const float* __restrict__ z0, const float* __restrict__ z1,
                        const float* __restrict__ T0, const float* __restrict__ T1,
                        const float* __restrict__ b2, float* __restrict__ out) {
    int n = blockIdx.x * blockDim.x + threadIdx.x;
    if (n >= N_NODES) return;
    float di = dinv[n];
    out[2 * n]     = di * (T0[n] + z0[n]) + b2[0];
    out[2 * n + 1] = di * (T1[n] + z1[n]) + b2[1];
}

// ---------------- launch ----------------

extern "C" void kernel_launch(void* const* d_in, const int* in_sizes, int n_in,
                              void* d_out, int out_size, void* d_ws, size_t ws_size,
                              hipStream_t stream) {
    const float* x   = (const float*)d_in[0];            // [50000,1]
    const int*   ei  = (const int*)d_in[1];              // [2,800000] row-major
    const float* W1  = (const float*)d_in[2];            // [1,64]
    const float* b1  = (const float*)d_in[3];            // [64]
    const float* W2  = (const float*)d_in[4];            // [64,2]
    const float* b2  = (const float*)d_in[5];            // [2]
    float* out = (float*)d_out;                          // [50000,2]

    const int* row = ei;
    const int* col = ei + N_EDGES;

    // ws layout (floats): [cnt(int) | t | T0 | T1 | dinv | z0 | z1]
    float* ws = (float*)d_ws;
    int*   cnt  = (int*)ws;                 // N (zeroed)
    float* t    = ws + 1 * N_NODES;         // N (zeroed)
    float* T0   = ws + 2 * N_NODES;         // N (zeroed)
    float* T1   = ws + 3 * N_NODES;         // N (zeroed)
    float* dinv = ws + 4 * N_NODES;
    float* z0   = ws + 5 * N_NODES;
    float* z1   = ws + 6 * N_NODES;

    const int B = 256;
    const int gN = (N_NODES + B - 1) / B;
    const int gE = (N_EDGES + B - 1) / B;
    const int gZ = (4 * N_NODES + B - 1) / B;

    k_zero<<<gZ, B, 0, stream>>>(ws, 4 * N_NODES);   // cnt, t, T0, T1
    k_deg<<<gE, B, 0, stream>>>(col, cnt);
    k_dinv<<<gN, B, 0, stream>>>(cnt, dinv);
    k_scatter1<<<gE, B, 0, stream>>>(row, col, x, dinv, t);
    k_y<<<gN, B, 0, stream>>>(x, dinv, t, W1, b1, W2, z0, z1);
    k_scatter2<<<gE, B, 0, stream>>>(row, col, z0, z1, T0, T1);
    k_final<<<gN, B, 0, stream>>>(dinv, z0, z1, T0, T1, b2, out);
}

// Round 2
// 147.851 us; speedup vs baseline: 1.6501x; 1.6501x over previous
//
#include <hip/hip_runtime.h>
#include <math.h>

#define N_NODES 50000
#define N_EDGES 800000
#define HIDDEN  64
#define NBLK    ((N_NODES + 255) / 256)   // 196 scan blocks

// ================= common =================

__global__ void k_zero_i(int* p, int n) {
    int i = blockIdx.x * blockDim.x + threadIdx.x;
    if (i < n) p[i] = 0;
}

// ================= fast path: counting-sort + gather =================

// rank[e] = old count; cnt ends as in-degree (self-loop excluded)
__global__ void k_deg_rank(const int* __restrict__ col, int* __restrict__ cnt,
                           int* __restrict__ rank) {
    int e = blockIdx.x * blockDim.x + threadIdx.x;
    if (e < N_EDGES) rank[e] = atomicAdd(&cnt[col[e]], 1);
}

__global__ void k_scanA(const int* __restrict__ cnt, int* __restrict__ blockSum) {
    __shared__ int s[256];
    int t = threadIdx.x;
    int i = blockIdx.x * 256 + t;
    s[t] = (i < N_NODES) ? cnt[i] : 0;
    __syncthreads();
    for (int off = 128; off > 0; off >>= 1) {
        if (t < off) s[t] += s[t + off];
        __syncthreads();
    }
    if (t == 0) blockSum[blockIdx.x] = s[0];
}

__global__ void k_scanB(int* __restrict__ blockSum) {
    __shared__ int s[256];
    int t = threadIdx.x;
    s[t] = (t < NBLK) ? blockSum[t] : 0;
    __syncthreads();
    if (t == 0) {
        int acc = 0;
        for (int i = 0; i < NBLK; ++i) { int v = s[i]; s[i] = acc; acc += v; }
    }
    __syncthreads();
    if (t < NBLK) blockSum[t] = s[t];   // exclusive block bases
}

// per-block exclusive scan + dinv + g = dinv*x
__global__ void k_scanC(const int* __restrict__ cnt, const int* __restrict__ blockBase,
                        const float* __restrict__ x,
                        int* __restrict__ base, float* __restrict__ dinv,
                        float* __restrict__ g) {
    __shared__ int s[256];
    int t = threadIdx.x;
    int i = blockIdx.x * 256 + t;
    int v = (i < N_NODES) ? cnt[i] : 0;
    s[t] = v;
    __syncthreads();
    for (int off = 1; off < 256; off <<= 1) {
        int add = (t >= off) ? s[t - off] : 0;
        __syncthreads();
        s[t] += add;
        __syncthreads();
    }
    if (i < N_NODES) {
        base[i] = s[t] - v + blockBase[blockIdx.x];
        float di = rsqrtf((float)(v + 1));
        dinv[i] = di;
        g[i] = di * x[i];
    }
}

__global__ void k_place(const int* __restrict__ row, const int* __restrict__ col,
                        const int* __restrict__ rank, const int* __restrict__ base,
                        int* __restrict__ srow) {
    int e = blockIdx.x * blockDim.x + threadIdx.x;
    if (e < N_EDGES) srow[base[col[e]] + rank[e]] = row[e];
}

// gather agg1 + MLP: s = dinv*(sum g[src] + g[n]); h=relu(s*W1+b1); y=h@W2; z=dinv*y
__global__ void k_layer1(const int* __restrict__ srow, const int* __restrict__ base,
                         const int* __restrict__ cnt, const float* __restrict__ g,
                         const float* __restrict__ dinv,
                         const float* __restrict__ W1, const float* __restrict__ b1,
                         const float* __restrict__ W2, float2* __restrict__ z) {
    int n = blockIdx.x * blockDim.x + threadIdx.x;
    if (n >= N_NODES) return;
    int b = base[n], d = cnt[n];
    float t = 0.0f;
    for (int j = 0; j < d; ++j) t += g[srow[b + j]];
    float di = dinv[n];
    float s = di * (t + g[n]);
    float y0 = 0.0f, y1 = 0.0f;
#pragma unroll
    for (int j = 0; j < HIDDEN; ++j) {
        float h = fmaxf(s * W1[j] + b1[j], 0.0f);
        y0 += h * W2[2 * j];
        y1 += h * W2[2 * j + 1];
    }
    z[n] = make_float2(di * y0, di * y1);
}

// gather agg2 + epilogue
__global__ void k_layer2(const int* __restrict__ srow, const int* __restrict__ base,
                         const int* __restrict__ cnt, const float2* __restrict__ z,
                         const float* __restrict__ dinv, const float* __restrict__ b2,
                         float* __restrict__ out) {
    int n = blockIdx.x * blockDim.x + threadIdx.x;
    if (n >= N_NODES) return;
    int b = base[n], d = cnt[n];
    float T0 = 0.0f, T1 = 0.0f;
    for (int j = 0; j < d; ++j) {
        float2 v = z[srow[b + j]];
        T0 += v.x; T1 += v.y;
    }
    float di = dinv[n];
    float2 zn = z[n];
    out[2 * n]     = di * (T0 + zn.x) + b2[0];
    out[2 * n + 1] = di * (T1 + zn.y) + b2[1];
}

// ================= fallback path (R1 atomics version) =================

__global__ void k_zero_f(float* p, int n) {
    int i = blockIdx.x * blockDim.x + threadIdx.x;
    if (i < n) p[i] = 0.0f;
}
__global__ void fb_deg(const int* __restrict__ col, int* __restrict__ cnt) {
    int e = blockIdx.x * blockDim.x + threadIdx.x;
    if (e < N_EDGES) atomicAdd(&cnt[col[e]], 1);
}
__global__ void fb_dinv(const int* __restrict__ cnt, float* __restrict__ dinv) {
    int i = blockIdx.x * blockDim.x + threadIdx.x;
    if (i < N_NODES) dinv[i] = rsqrtf((float)(cnt[i] + 1));
}
__global__ void fb_scatter1(const int* __restrict__ row, const int* __restrict__ col,
                            const float* __restrict__ x, const float* __restrict__ dinv,
                            float* __restrict__ t) {
    int e = blockIdx.x * blockDim.x + threadIdx.x;
    if (e < N_EDGES) { int r = row[e], c = col[e]; atomicAdd(&t[c], dinv[r] * x[r]); }
}
__global__ void fb_y(const float* __restrict__ x, const float* __restrict__ dinv,
                     const float* __restrict__ t, const float* __restrict__ W1,
                     const float* __restrict__ b1, const float* __restrict__ W2,
                     float* __restrict__ z0, float* __restrict__ z1) {
    int n = blockIdx.x * blockDim.x + threadIdx.x;
    if (n >= N_NODES) return;
    float di = dinv[n];
    float s = di * (t[n] + di * x[n]);
    float y0 = 0.0f, y1 = 0.0f;
#pragma unroll
    for (int j = 0; j < HIDDEN; ++j) {
        float h = fmaxf(s * W1[j] + b1[j], 0.0f);
        y0 += h * W2[2 * j]; y1 += h * W2[2 * j + 1];
    }
    z0[n] = di * y0; z1[n] = di * y1;
}
__global__ void fb_scatter2(const int* __restrict__ row, const int* __restrict__ col,
                            const float* __restrict__ z0, const float* __restrict__ z1,
                            float* __restrict__ T0, float* __restrict__ T1) {
    int e = blockIdx.x * blockDim.x + threadIdx.x;
    if (e < N_EDGES) {
        int r = row[e], c = col[e];
        atomicAdd(&T0[c], z0[r]); atomicAdd(&T1[c], z1[r]);
    }
}
__global__ void fb_final(const float* __restrict__ dinv, const float* __restrict__ z0,
                         const float* __restrict__ z1, const float* __restrict__ T0,
                         const float* __restrict__ T1, const float* __restrict__ b2,
                         float* __restrict__ out) {
    int n = blockIdx.x * blockDim.x + threadIdx.x;
    if (n >= N_NODES) return;
    float di = dinv[n];
    out[2 * n]     = di * (T0[n] + z0[n]) + b2[0];
    out[2 * n + 1] = di * (T1[n] + z1[n]) + b2[1];
}

// ================= launch =================

extern "C" void kernel_launch(void* const* d_in, const int* in_sizes, int n_in,
                              void* d_out, int out_size, void* d_ws, size_t ws_size,
                              hipStream_t stream) {
    const float* x  = (const float*)d_in[0];
    const int*   ei = (const int*)d_in[1];
    const float* W1 = (const float*)d_in[2];
    const float* b1 = (const float*)d_in[3];
    const float* W2 = (const float*)d_in[4];
    const float* b2 = (const float*)d_in[5];
    float* out = (float*)d_out;

    const int* row = ei;
    const int* col = ei + N_EDGES;

    const int B = 256;
    const int gN = (N_NODES + B - 1) / B;
    const int gE = (N_EDGES + B - 1) / B;

    // fast-path ws layout (4-byte elements):
    // cnt[N] | base[N] | dinv[N] | g[N] | z[2N] | blockSum[256] | rank[E] | srow[E]
    const size_t need = (size_t)(6 * N_NODES + 256 + 2 * N_EDGES) * 4;

    if (ws_size >= need) {
        int*   ws   = (int*)d_ws;
        int*   cnt  = ws;
        int*   base = ws + N_NODES;
        float* dinv = (float*)(ws + 2 * N_NODES);
        float* g    = (float*)(ws + 3 * N_NODES);
        float2* z   = (float2*)(ws + 4 * N_NODES);
        int*   blockSum = ws + 6 * N_NODES;
        int*   rank = ws + 6 * N_NODES + 256;
        int*   srow = rank + N_EDGES;

        k_zero_i<<<gN, B, 0, stream>>>(cnt, N_NODES);
        k_deg_rank<<<gE, B, 0, stream>>>(col, cnt, rank);
        k_scanA<<<NBLK, B, 0, stream>>>(cnt, blockSum);
        k_scanB<<<1, B, 0, stream>>>(blockSum);
        k_scanC<<<NBLK, B, 0, stream>>>(cnt, blockSum, x, base, dinv, g);
        k_place<<<gE, B, 0, stream>>>(row, col, rank, base, srow);
        k_layer1<<<gN, B, 0, stream>>>(srow, base, cnt, g, dinv, W1, b1, W2, z);
        k_layer2<<<gN, B, 0, stream>>>(srow, base, cnt, z, dinv, b2, out);
    } else {
        // fallback: R1 atomic path (needs 7N floats)
        float* ws = (float*)d_ws;
        int*   cnt  = (int*)ws;
        float* t    = ws + 1 * N_NODES;
        float* T0   = ws + 2 * N_NODES;
        float* T1   = ws + 3 * N_NODES;
        float* dinv = ws + 4 * N_NODES;
        float* z0   = ws + 5 * N_NODES;
        float* z1   = ws + 6 * N_NODES;
        const int gZ = (4 * N_NODES + B - 1) / B;

        k_zero_f<<<gZ, B, 0, stream>>>((float*)d_ws, 4 * N_NODES);
        fb_deg<<<gE, B, 0, stream>>>(col, cnt);
        fb_dinv<<<gN, B, 0, stream>>>(cnt, dinv);
        fb_scatter1<<<gE, B, 0, stream>>>(row, col, x, dinv, t);
        fb_y<<<gN, B, 0, stream>>>(x, dinv, t, W1, b1, W2, z0, z1);
        fb_scatter2<<<gE, B, 0, stream>>>(row, col, z0, z1, T0, T1);
        fb_final<<<gN, B, 0, stream>>>(dinv, z0, z1, T0, T1, b2, out);
    }
}